// Round 4
// baseline (252.598 us; speedup 1.0000x reference)
//
#include <hip/hip_runtime.h>

// YOLO-v1 loss forward, S=7, B=2, C=20, bs=16384.
// 193 MB in -> 4 B out; m13-proven streaming ceiling ~6.3 TB/s aggregate.
// R4: occupancy + MLP attack on the 2.5 TB/s plateau.
//   - slab = 160 cells -> 19.2 KB LDS -> 8 blocks/CU = 32 waves/CU (was 20)
//   - explicit tmp[5] load-all-then-write-all staging (>=5 float4 in flight
//     per wave; R3's VGPR=44 proved the compiler held only ~2)
//   - grid = 2048 = exact full residency; per-block partials -> d_ws

#define SS 7
#define CELL_STRIDE 30                 // 5*B + C floats per cell
#define CELLS_PER_SLAB 160
#define FLOATS_PER_SLAB (CELLS_PER_SLAB * CELL_STRIDE)   // 4800 (19200 B)
#define V4_PER_SLAB (FLOATS_PER_SLAB / 4)                // 1200
#define NBLOCKS 2048

__device__ __forceinline__ float yolo_cell_loss(const float* pv, const float* lv, int cell) {
    const int rem = cell % (SS * SS);
    const float gx = (float)(rem % SS);   // meshgrid 'xy': x = col
    const float gy = (float)(rem / SS);   // y = row

    const float obj = lv[4];
    const float lx = lv[0], ly = lv[1], lw = lv[2], lh = lv[3];
    const float l_cx = (gx + lx) / 7.0f;
    const float l_cy = (gy + ly) / 7.0f;
    const float l_minx = l_cx - lw * 0.5f, l_maxx = l_cx + lw * 0.5f;
    const float l_miny = l_cy - lh * 0.5f, l_maxy = l_cy + lh * 0.5f;
    const float area_l = lw * lh;

    float iou[2], box_err[2], conf[2];
    #pragma unroll
    for (int b = 0; b < 2; ++b) {
        const float px = pv[5 * b + 0], py = pv[5 * b + 1];
        const float pw = pv[5 * b + 2], ph = pv[5 * b + 3];
        conf[b] = pv[5 * b + 4];
        const float p_cx = (gx + px) / 7.0f;
        const float p_cy = (gy + py) / 7.0f;
        const float p_minx = p_cx - pw * 0.5f, p_maxx = p_cx + pw * 0.5f;
        const float p_miny = p_cy - ph * 0.5f, p_maxy = p_cy + ph * 0.5f;
        float iw = fminf(p_maxx, l_maxx) - fmaxf(p_minx, l_minx);
        float ih = fminf(p_maxy, l_maxy) - fmaxf(p_miny, l_miny);
        iw = fmaxf(iw, 0.0f); ih = fmaxf(ih, 0.0f);
        const float inter = iw * ih;
        const float uni = pw * ph + area_l - inter + 1e-10f;
        iou[b] = inter / uni;
        const float dx = px - lx, dy = py - ly;
        const float dw = sqrtf(pw) - sqrtf(lw);
        const float dh = sqrtf(ph) - sqrtf(lh);
        box_err[b] = (dx * dx + dy * dy) + (dw * dw + dh * dh);
    }

    // argmax tie-break: first max wins -> box 1 only if strictly greater
    const int r = (iou[1] > iou[0]) ? 1 : 0;
    const float cr = conf[r], cn = conf[1 - r];

    float loss = obj * (5.0f * box_err[r] + (cr - iou[r]) * (cr - iou[r]));
    loss += 0.5f * ((1.0f - obj) * cr * cr + cn * cn);

    float cls = 0.0f;
    #pragma unroll
    for (int k = 10; k < 30; ++k) {
        const float d = pv[k] - lv[k];
        cls += d * d;
    }
    loss += obj * cls;
    return loss;
}

// stage nv4 float4s (coalesced, >=5 in flight), barrier handled by caller
__device__ __forceinline__ void stage_slab(const float4* __restrict__ g,
                                           float4* __restrict__ s4,
                                           int tid, int nv4) {
    float4 tmp[5];
    #pragma unroll
    for (int k = 0; k < 5; ++k) {
        const int i = tid + k * 256;
        if (i < nv4) tmp[k] = g[i];
    }
    #pragma unroll
    for (int k = 0; k < 5; ++k) {
        const int i = tid + k * 256;
        if (i < nv4) s4[i] = tmp[k];
    }
}

__global__ __launch_bounds__(256) void yolo_loss_partial(
    const float* __restrict__ preds,
    const float* __restrict__ labels,
    float* __restrict__ partial,
    int ncells, int nslabs, float inv_bs, int use_atomic)
{
    __shared__ float sh[FLOATS_PER_SLAB];   // 19200 B -> 8 blocks/CU
    float4* s4 = reinterpret_cast<float4*>(sh);
    const int tid = threadIdx.x;
    float acc = 0.0f;

    for (int slab = blockIdx.x; slab < nslabs; slab += NBLOCKS) {
        const int cell0 = slab * CELLS_PER_SLAB;
        const int cells = min(CELLS_PER_SLAB, ncells - cell0);   // 160 or 96 (tail)
        const int nv4 = cells * (CELL_STRIDE / 2) / 2;           // cells*7.5
        const size_t base = (size_t)cell0 * CELL_STRIDE;

        // ---- preds phase ----
        stage_slab(reinterpret_cast<const float4*>(preds + base), s4, tid, nv4);
        __syncthreads();
        float pv[CELL_STRIDE];
        if (tid < cells) {
            const float* myp = sh + tid * CELL_STRIDE;
            #pragma unroll
            for (int k = 0; k < 15; ++k) {
                float2 t = *reinterpret_cast<const float2*>(myp + 2 * k);
                pv[2 * k] = t.x; pv[2 * k + 1] = t.y;
            }
        }
        __syncthreads();

        // ---- labels phase ----
        stage_slab(reinterpret_cast<const float4*>(labels + base), s4, tid, nv4);
        __syncthreads();
        if (tid < cells) {
            float lv[CELL_STRIDE];
            const float* myl = sh + tid * CELL_STRIDE;
            #pragma unroll
            for (int k = 0; k < 3; ++k) {
                float2 t = *reinterpret_cast<const float2*>(myl + 2 * k);
                lv[2 * k] = t.x; lv[2 * k + 1] = t.y;
            }
            #pragma unroll
            for (int k = 5; k < 15; ++k) {
                float2 t = *reinterpret_cast<const float2*>(myl + 2 * k);
                lv[2 * k] = t.x; lv[2 * k + 1] = t.y;
            }
            acc += yolo_cell_loss(pv, lv, cell0 + tid);
        }
        __syncthreads();   // protect sh before next slab's staging
    }

    acc *= inv_bs;

    // wave (64-lane) shuffle reduction
    #pragma unroll
    for (int off = 32; off > 0; off >>= 1)
        acc += __shfl_down(acc, off, 64);

    __shared__ float wsum[4];
    const int lane = tid & 63;
    const int wid  = tid >> 6;
    if (lane == 0) wsum[wid] = acc;
    __syncthreads();
    if (tid == 0) {
        const float blocksum = wsum[0] + wsum[1] + wsum[2] + wsum[3];
        if (use_atomic) atomicAdd(partial, blocksum);        // fallback: partial==out
        else            partial[blockIdx.x] = blocksum;
    }
}

__global__ __launch_bounds__(256) void yolo_reduce(
    const float* __restrict__ partial, float* __restrict__ out, int n)
{
    float acc = 0.0f;
    for (int i = threadIdx.x; i < n; i += 256) acc += partial[i];
    #pragma unroll
    for (int off = 32; off > 0; off >>= 1)
        acc += __shfl_down(acc, off, 64);
    __shared__ float wsum[4];
    const int lane = threadIdx.x & 63;
    const int wid  = threadIdx.x >> 6;
    if (lane == 0) wsum[wid] = acc;
    __syncthreads();
    if (threadIdx.x == 0) out[0] = wsum[0] + wsum[1] + wsum[2] + wsum[3];
}

__global__ void yolo_zero_out(float* out) {
    if (threadIdx.x == 0) out[0] = 0.0f;
}

extern "C" void kernel_launch(void* const* d_in, const int* in_sizes, int n_in,
                              void* d_out, int out_size, void* d_ws, size_t ws_size,
                              hipStream_t stream) {
    const float* preds  = (const float*)d_in[0];
    const float* labels = (const float*)d_in[1];
    float* out = (float*)d_out;

    const int ncells = in_sizes[0] / CELL_STRIDE;                 // 802816
    const int nslabs = (ncells + CELLS_PER_SLAB - 1) / CELLS_PER_SLAB;  // 5018
    const int bs     = ncells / (SS * SS);                        // 16384
    const float inv_bs = 1.0f / (float)bs;

    if (ws_size >= NBLOCKS * sizeof(float)) {
        float* partial = (float*)d_ws;
        yolo_loss_partial<<<NBLOCKS, 256, 0, stream>>>(preds, labels, partial,
                                                       ncells, nslabs, inv_bs, 0);
        yolo_reduce<<<1, 256, 0, stream>>>(partial, out, NBLOCKS);
    } else {
        yolo_zero_out<<<1, 64, 0, stream>>>(out);
        yolo_loss_partial<<<NBLOCKS, 256, 0, stream>>>(preds, labels, out,
                                                       ncells, nslabs, inv_bs, 1);
    }
}

// Round 6
// 209.206 us; speedup vs baseline: 1.2074x; 1.2074x over previous
//
#include <hip/hip_runtime.h>

// YOLO-v1 loss forward, S=7, B=2, C=20, bs=16384.
// R6: R5's barrier-free wave-private LDS staging, fixed.
//   R5 post-mortem: HW LDS is in-order per wave, but LLVM's *scalar* alias
//   analysis can't see the cross-lane dependence of the transpose and
//   reordered LDS phases -> absmax 37.5. Fix: __builtin_amdgcn_wave_barrier()
//   + wavefront-scope fence at each LDS phase boundary. Zero HW cost: no
//   s_barrier, waves in a block stay fully independent (the actual experiment:
//   does removing barrier convoying break the ~78us plateau?).

#define SS 7
#define CELL_STRIDE 30                       // 5*B + C floats per cell
#define CELLS_PER_WAVE 64
#define WAVE_FLOATS (CELLS_PER_WAVE * CELL_STRIDE)   // 1920 floats = 7680 B
#define SLAB_CELLS 256
#define NBLOCKS 1280                          // 5 blocks/CU at 30.7 KB LDS

// compiler-only ordering for intra-wave cross-lane LDS exchange:
// wave_barrier emits no instruction; fence(wavefront) orders memory at wave
// scope (free in HW: per-wave LDS pipeline is in-order).
__device__ __forceinline__ void wave_lds_fence() {
    __builtin_amdgcn_fence(__ATOMIC_SEQ_CST, "wavefront");
    __builtin_amdgcn_wave_barrier();
}

__device__ __forceinline__ float yolo_cell_loss(const float* pv, const float* lv, int cell) {
    const int rem = cell % (SS * SS);
    const float gx = (float)(rem % SS);   // meshgrid 'xy': x = col
    const float gy = (float)(rem / SS);   // y = row

    const float obj = lv[4];
    const float lx = lv[0], ly = lv[1], lw = lv[2], lh = lv[3];
    const float l_cx = (gx + lx) / 7.0f;
    const float l_cy = (gy + ly) / 7.0f;
    const float l_minx = l_cx - lw * 0.5f, l_maxx = l_cx + lw * 0.5f;
    const float l_miny = l_cy - lh * 0.5f, l_maxy = l_cy + lh * 0.5f;
    const float area_l = lw * lh;

    float iou[2], box_err[2], conf[2];
    #pragma unroll
    for (int b = 0; b < 2; ++b) {
        const float px = pv[5 * b + 0], py = pv[5 * b + 1];
        const float pw = pv[5 * b + 2], ph = pv[5 * b + 3];
        conf[b] = pv[5 * b + 4];
        const float p_cx = (gx + px) / 7.0f;
        const float p_cy = (gy + py) / 7.0f;
        const float p_minx = p_cx - pw * 0.5f, p_maxx = p_cx + pw * 0.5f;
        const float p_miny = p_cy - ph * 0.5f, p_maxy = p_cy + ph * 0.5f;
        float iw = fminf(p_maxx, l_maxx) - fmaxf(p_minx, l_minx);
        float ih = fminf(p_maxy, l_maxy) - fmaxf(p_miny, l_miny);
        iw = fmaxf(iw, 0.0f); ih = fmaxf(ih, 0.0f);
        const float inter = iw * ih;
        const float uni = pw * ph + area_l - inter + 1e-10f;
        iou[b] = inter / uni;
        const float dx = px - lx, dy = py - ly;
        const float dw = sqrtf(pw) - sqrtf(lw);
        const float dh = sqrtf(ph) - sqrtf(lh);
        box_err[b] = (dx * dx + dy * dy) + (dw * dw + dh * dh);
    }

    // argmax tie-break: first max wins -> box 1 only if strictly greater
    const int r = (iou[1] > iou[0]) ? 1 : 0;
    const float cr = conf[r], cn = conf[1 - r];

    float loss = obj * (5.0f * box_err[r] + (cr - iou[r]) * (cr - iou[r]));
    loss += 0.5f * ((1.0f - obj) * cr * cr + cn * cn);

    float cls = 0.0f;
    #pragma unroll
    for (int k = 10; k < 30; ++k) {
        const float d = pv[k] - lv[k];
        cls += d * d;
    }
    loss += obj * cls;
    return loss;
}

__global__ __launch_bounds__(256) void yolo_loss_partial(
    const float* __restrict__ preds,
    const float* __restrict__ labels,
    float* __restrict__ partial,
    int nslabs, float inv_bs, int use_atomic)
{
    __shared__ float sh[4 * WAVE_FLOATS];    // 30720 B -> 5 blocks/CU (LDS)
    const int tid  = threadIdx.x;
    const int lane = tid & 63;
    const int wid  = tid >> 6;
    float*  wsh  = sh + wid * WAVE_FLOATS;   // this wave's private segment
    float2* wsh2 = reinterpret_cast<float2*>(wsh);

    float acc = 0.0f;

    for (int slab = blockIdx.x; slab < nslabs; slab += NBLOCKS) {
        const int cell0 = slab * SLAB_CELLS + wid * CELLS_PER_WAVE;
        const float2* gp = reinterpret_cast<const float2*>(preds  + (size_t)cell0 * CELL_STRIDE);
        const float2* gl = reinterpret_cast<const float2*>(labels + (size_t)cell0 * CELL_STRIDE);

        // ---- stage preds tile (coalesced, wave-private) ----
        float2 t[15];
        #pragma unroll
        for (int k = 0; k < 15; ++k) t[k] = gp[lane + 64 * k];
        #pragma unroll
        for (int k = 0; k < 15; ++k) wsh2[lane + 64 * k] = t[k];
        wave_lds_fence();   // writes (all lanes) before reads

        // ---- my cell's preds (cross-lane through LDS) ----
        float pv[CELL_STRIDE];
        {
            const float2* my = reinterpret_cast<const float2*>(wsh + lane * CELL_STRIDE);
            #pragma unroll
            for (int k = 0; k < 15; ++k) { float2 v = my[k]; pv[2*k] = v.x; pv[2*k+1] = v.y; }
        }
        wave_lds_fence();   // reads done before segment is overwritten

        // ---- stage labels tile into same segment ----
        #pragma unroll
        for (int k = 0; k < 15; ++k) t[k] = gl[lane + 64 * k];
        #pragma unroll
        for (int k = 0; k < 15; ++k) wsh2[lane + 64 * k] = t[k];
        wave_lds_fence();   // writes before reads

        // ---- my cell's labels ----
        float lv[CELL_STRIDE];
        {
            const float2* my = reinterpret_cast<const float2*>(wsh + lane * CELL_STRIDE);
            #pragma unroll
            for (int k = 0; k < 3; ++k)  { float2 v = my[k]; lv[2*k] = v.x; lv[2*k+1] = v.y; }
            #pragma unroll
            for (int k = 5; k < 15; ++k) { float2 v = my[k]; lv[2*k] = v.x; lv[2*k+1] = v.y; }
        }
        wave_lds_fence();   // reads done before next slab overwrites

        acc += yolo_cell_loss(pv, lv, cell0 + lane);
    }

    acc *= inv_bs;

    // wave (64-lane) shuffle reduction
    #pragma unroll
    for (int off = 32; off > 0; off >>= 1)
        acc += __shfl_down(acc, off, 64);

    __shared__ float wsum[4];
    if (lane == 0) wsum[wid] = acc;
    __syncthreads();
    if (tid == 0) {
        const float blocksum = wsum[0] + wsum[1] + wsum[2] + wsum[3];
        if (use_atomic) atomicAdd(partial, blocksum);        // fallback: partial==out
        else            partial[blockIdx.x] = blocksum;
    }
}

__global__ __launch_bounds__(256) void yolo_reduce(
    const float* __restrict__ partial, float* __restrict__ out, int n)
{
    float acc = 0.0f;
    for (int i = threadIdx.x; i < n; i += 256) acc += partial[i];
    #pragma unroll
    for (int off = 32; off > 0; off >>= 1)
        acc += __shfl_down(acc, off, 64);
    __shared__ float wsum[4];
    const int lane = threadIdx.x & 63;
    const int wid  = threadIdx.x >> 6;
    if (lane == 0) wsum[wid] = acc;
    __syncthreads();
    if (threadIdx.x == 0) out[0] = wsum[0] + wsum[1] + wsum[2] + wsum[3];
}

__global__ void yolo_zero_out(float* out) {
    if (threadIdx.x == 0) out[0] = 0.0f;
}

extern "C" void kernel_launch(void* const* d_in, const int* in_sizes, int n_in,
                              void* d_out, int out_size, void* d_ws, size_t ws_size,
                              hipStream_t stream) {
    const float* preds  = (const float*)d_in[0];
    const float* labels = (const float*)d_in[1];
    float* out = (float*)d_out;

    const int ncells = in_sizes[0] / CELL_STRIDE;        // 802816 (divisible by 256)
    const int nslabs = ncells / SLAB_CELLS;              // 3136
    const int bs     = ncells / (SS * SS);               // 16384
    const float inv_bs = 1.0f / (float)bs;

    if (ws_size >= NBLOCKS * sizeof(float)) {
        float* partial = (float*)d_ws;
        yolo_loss_partial<<<NBLOCKS, 256, 0, stream>>>(preds, labels, partial,
                                                       nslabs, inv_bs, 0);
        yolo_reduce<<<1, 256, 0, stream>>>(partial, out, NBLOCKS);
    } else {
        yolo_zero_out<<<1, 64, 0, stream>>>(out);
        yolo_loss_partial<<<NBLOCKS, 256, 0, stream>>>(preds, labels, out,
                                                       nslabs, inv_bs, 1);
    }
}

// Round 7
// 207.736 us; speedup vs baseline: 1.2160x; 1.0071x over previous
//
#include <hip/hip_runtime.h>

// YOLO-v1 loss forward, S=7, B=2, C=20, bs=16384.
// R7: max-MLP x max-TLP probe of the ~2.6 TB/s plateau.
//   - All 30 dwordx2 loads (preds+labels) issued before any LDS op:
//     15.4 KB in flight per wave, ONE vmcnt drain region per slab (R6 had two).
//   - Block=128 (2 waves, 15.4 KB LDS): VGPR-capped at 4 waves/SIMD -> 16
//     waves/CU (R6 measured ~10 effective). 2560 blocks.
//   - Barrier-free wave-private LDS transpose w/ wave_barrier+wavefront fence
//     (R6-proven correct). If this lands ~70-75 us again, the plateau is an
//     external wall (L3 churn from harness restore), i.e. the roofline.

#define SS 7
#define CELL_STRIDE 30                       // 5*B + C floats per cell
#define WAVE_FLOATS (64 * CELL_STRIDE)       // 1920 floats = 7680 B
#define WAVES_PER_BLOCK 2
#define SLAB_CELLS (64 * WAVES_PER_BLOCK)    // 128
#define NBLOCKS 2560                         // 10 blocks/CU at 15.4 KB LDS

__device__ __forceinline__ void wave_lds_fence() {
    __builtin_amdgcn_fence(__ATOMIC_SEQ_CST, "wavefront");
    __builtin_amdgcn_wave_barrier();
}

__device__ __forceinline__ float yolo_cell_loss(const float* pv, const float* lv, int cell) {
    const int rem = cell % (SS * SS);
    const float gx = (float)(rem % SS);   // meshgrid 'xy': x = col
    const float gy = (float)(rem / SS);   // y = row

    const float obj = lv[4];
    const float lx = lv[0], ly = lv[1], lw = lv[2], lh = lv[3];
    const float l_cx = (gx + lx) / 7.0f;
    const float l_cy = (gy + ly) / 7.0f;
    const float l_minx = l_cx - lw * 0.5f, l_maxx = l_cx + lw * 0.5f;
    const float l_miny = l_cy - lh * 0.5f, l_maxy = l_cy + lh * 0.5f;
    const float area_l = lw * lh;

    float iou[2], box_err[2], conf[2];
    #pragma unroll
    for (int b = 0; b < 2; ++b) {
        const float px = pv[5 * b + 0], py = pv[5 * b + 1];
        const float pw = pv[5 * b + 2], ph = pv[5 * b + 3];
        conf[b] = pv[5 * b + 4];
        const float p_cx = (gx + px) / 7.0f;
        const float p_cy = (gy + py) / 7.0f;
        const float p_minx = p_cx - pw * 0.5f, p_maxx = p_cx + pw * 0.5f;
        const float p_miny = p_cy - ph * 0.5f, p_maxy = p_cy + ph * 0.5f;
        float iw = fminf(p_maxx, l_maxx) - fmaxf(p_minx, l_minx);
        float ih = fminf(p_maxy, l_maxy) - fmaxf(p_miny, l_miny);
        iw = fmaxf(iw, 0.0f); ih = fmaxf(ih, 0.0f);
        const float inter = iw * ih;
        const float uni = pw * ph + area_l - inter + 1e-10f;
        iou[b] = inter / uni;
        const float dx = px - lx, dy = py - ly;
        const float dw = sqrtf(pw) - sqrtf(lw);
        const float dh = sqrtf(ph) - sqrtf(lh);
        box_err[b] = (dx * dx + dy * dy) + (dw * dw + dh * dh);
    }

    // argmax tie-break: first max wins -> box 1 only if strictly greater
    const int r = (iou[1] > iou[0]) ? 1 : 0;
    const float cr = conf[r], cn = conf[1 - r];

    float loss = obj * (5.0f * box_err[r] + (cr - iou[r]) * (cr - iou[r]));
    loss += 0.5f * ((1.0f - obj) * cr * cr + cn * cn);

    float cls = 0.0f;
    #pragma unroll
    for (int k = 10; k < 30; ++k) {
        const float d = pv[k] - lv[k];
        cls += d * d;
    }
    loss += obj * cls;
    return loss;
}

__global__ __launch_bounds__(128) void yolo_loss_partial(
    const float* __restrict__ preds,
    const float* __restrict__ labels,
    float* __restrict__ partial,
    int nslabs, float inv_bs, int use_atomic)
{
    __shared__ float sh[WAVES_PER_BLOCK * WAVE_FLOATS];   // 15360 B
    const int tid  = threadIdx.x;
    const int lane = tid & 63;
    const int wid  = tid >> 6;
    float*  wsh  = sh + wid * WAVE_FLOATS;   // this wave's private segment
    float2* wsh2 = reinterpret_cast<float2*>(wsh);

    float acc = 0.0f;

    for (int slab = blockIdx.x; slab < nslabs; slab += NBLOCKS) {
        const int cell0 = slab * SLAB_CELLS + wid * 64;
        const float2* gp = reinterpret_cast<const float2*>(preds  + (size_t)cell0 * CELL_STRIDE);
        const float2* gl = reinterpret_cast<const float2*>(labels + (size_t)cell0 * CELL_STRIDE);

        // ---- issue ALL 30 loads up front (15.4 KB in flight, one drain) ----
        float2 t[15], u[15];
        #pragma unroll
        for (int k = 0; k < 15; ++k) t[k] = gp[lane + 64 * k];
        #pragma unroll
        for (int k = 0; k < 15; ++k) u[k] = gl[lane + 64 * k];

        // ---- preds: LDS transpose (wave-private, no HW barrier) ----
        #pragma unroll
        for (int k = 0; k < 15; ++k) wsh2[lane + 64 * k] = t[k];
        wave_lds_fence();   // writes before cross-lane reads
        float pv[CELL_STRIDE];
        {
            const float2* my = reinterpret_cast<const float2*>(wsh + lane * CELL_STRIDE);
            #pragma unroll
            for (int k = 0; k < 15; ++k) { float2 v = my[k]; pv[2*k] = v.x; pv[2*k+1] = v.y; }
        }
        wave_lds_fence();   // reads done before overwrite

        // ---- labels: same segment ----
        #pragma unroll
        for (int k = 0; k < 15; ++k) wsh2[lane + 64 * k] = u[k];
        wave_lds_fence();
        float lv[CELL_STRIDE];
        {
            const float2* my = reinterpret_cast<const float2*>(wsh + lane * CELL_STRIDE);
            #pragma unroll
            for (int k = 0; k < 3; ++k)  { float2 v = my[k]; lv[2*k] = v.x; lv[2*k+1] = v.y; }
            #pragma unroll
            for (int k = 5; k < 15; ++k) { float2 v = my[k]; lv[2*k] = v.x; lv[2*k+1] = v.y; }
        }
        wave_lds_fence();   // reads done before next slab

        acc += yolo_cell_loss(pv, lv, cell0 + lane);
    }

    acc *= inv_bs;

    // wave (64-lane) shuffle reduction
    #pragma unroll
    for (int off = 32; off > 0; off >>= 1)
        acc += __shfl_down(acc, off, 64);

    __shared__ float wsum[WAVES_PER_BLOCK];
    if (lane == 0) wsum[wid] = acc;
    __syncthreads();
    if (tid == 0) {
        const float blocksum = wsum[0] + wsum[1];
        if (use_atomic) atomicAdd(partial, blocksum);        // fallback: partial==out
        else            partial[blockIdx.x] = blocksum;
    }
}

__global__ __launch_bounds__(256) void yolo_reduce(
    const float* __restrict__ partial, float* __restrict__ out, int n)
{
    float acc = 0.0f;
    for (int i = threadIdx.x; i < n; i += 256) acc += partial[i];
    #pragma unroll
    for (int off = 32; off > 0; off >>= 1)
        acc += __shfl_down(acc, off, 64);
    __shared__ float wsum[4];
    const int lane = threadIdx.x & 63;
    const int wid  = threadIdx.x >> 6;
    if (lane == 0) wsum[wid] = acc;
    __syncthreads();
    if (threadIdx.x == 0) out[0] = wsum[0] + wsum[1] + wsum[2] + wsum[3];
}

__global__ void yolo_zero_out(float* out) {
    if (threadIdx.x == 0) out[0] = 0.0f;
}

extern "C" void kernel_launch(void* const* d_in, const int* in_sizes, int n_in,
                              void* d_out, int out_size, void* d_ws, size_t ws_size,
                              hipStream_t stream) {
    const float* preds  = (const float*)d_in[0];
    const float* labels = (const float*)d_in[1];
    float* out = (float*)d_out;

    const int ncells = in_sizes[0] / CELL_STRIDE;        // 802816 (divisible by 128)
    const int nslabs = ncells / SLAB_CELLS;              // 6272
    const int bs     = ncells / (SS * SS);               // 16384
    const float inv_bs = 1.0f / (float)bs;

    if (ws_size >= NBLOCKS * sizeof(float)) {
        float* partial = (float*)d_ws;
        yolo_loss_partial<<<NBLOCKS, 128, 0, stream>>>(preds, labels, partial,
                                                       nslabs, inv_bs, 0);
        yolo_reduce<<<1, 256, 0, stream>>>(partial, out, NBLOCKS);
    } else {
        yolo_zero_out<<<1, 64, 0, stream>>>(out);
        yolo_loss_partial<<<NBLOCKS, 128, 0, stream>>>(preds, labels, out,
                                                       nslabs, inv_bs, 1);
    }
}